// Round 6
// baseline (581.730 us; speedup 1.0000x reference)
//
#include <hip/hip_runtime.h>
#include <hip/hip_bf16.h>

typedef __attribute__((ext_vector_type(8))) short short8;
typedef __attribute__((ext_vector_type(4))) float f32x4;
typedef unsigned short ushort_t;

// ---------------- prep ----------------------------------------------------

__device__ __forceinline__ ushort_t f2bf_rne(float f) {
    unsigned u = __float_as_uint(f);
    u += 0x7FFF + ((u >> 16) & 1);   // round-to-nearest-even
    return (ushort_t)(u >> 16);
}

__device__ __forceinline__ short8 pack8(float4 a, float4 b) {
    short8 r;
    r[0] = (short)f2bf_rne(a.x); r[1] = (short)f2bf_rne(a.y);
    r[2] = (short)f2bf_rne(a.z); r[3] = (short)f2bf_rne(a.w);
    r[4] = (short)f2bf_rne(b.x); r[5] = (short)f2bf_rne(b.y);
    r[6] = (short)f2bf_rne(b.z); r[7] = (short)f2bf_rne(b.w);
    return r;
}

// ROUND-10 conv: the bit-twiddle RNE pack was ~16 VALU instrs / 24B traffic
// -> VALU-bound at ~2.1 TB/s (layout-insensitive, R1 null). Swap to
// v_cvt_pk_bf16_f32 via __float22bfloat162_rn (1 instr / 2 floats, same RNE)
// -> conversion VALU cut ~4x, kernel becomes memory-bound-ish.
__global__ void conv_kernel(const float* __restrict__ src, ushort_t* __restrict__ dst) {
    long long base = (long long)blockIdx.x * 1024;
    const float4* s4 = (const float4*)src;
    uint2* d2 = (uint2*)dst;
    #pragma unroll
    for (int c = 0; c < 4; c++) {
        long long idx = base + c * 256 + threadIdx.x;
        float4 a = s4[idx];
        __hip_bfloat162 lo = __float22bfloat162_rn(make_float2(a.x, a.y));
        __hip_bfloat162 hi = __float22bfloat162_rn(make_float2(a.z, a.w));
        uint2 r;
        r.x = *reinterpret_cast<unsigned*>(&lo);   // a.x in low 16 bits
        r.y = *reinterpret_cast<unsigned*>(&hi);
        d2[idx] = r;
    }
}

__global__ void expect_kernel(const int* __restrict__ q, float* __restrict__ e,
                              int rows, int shots) {
    int row = blockIdx.x * (blockDim.x >> 6) + (threadIdx.x >> 6);
    int lane = threadIdx.x & 63;
    if (row >= rows) return;
    const int4* rp4 = (const int4*)(q + (long long)row * shots);
    int nvec = shots >> 2;                 // 250
    int s = 0;
    for (int j = lane; j < nvec; j += 64) {
        int4 v = rp4[j];
        s += v.x + v.y + v.z + v.w;
    }
    #pragma unroll
    for (int off = 32; off; off >>= 1) s += __shfl_down(s, off, 64);
    if (lane == 0) e[row] = (float)s * (1.0f / (1000.0f * 15.0f));
}

// ---------------------------------------------------------------------------
// ROUND-10 GEMM: 2-phase/2-barrier schedule with RESTORED LOAD SLACK.
// R5's regression mechanism (verified by timeline arithmetic): its kh1-end
// VMCNT(2) waited on B-kh0(t+1) issued ~400cyc earlier in the SAME phase
// (HBM lat ~900cyc) -> all-wave stall at a barrier every tile.
// Fix: issue ALL 8 loads of tile t+1 at the top of the kh0 phase.
//   steady state per wave:
//   kh0(t): [out: <=2 = B-kh1(t)] issue 8 of t+1 -> <=10; reads kh0 (landed:
//           vmcnt(2) of kh1(t-1) retired first 6 of tile t); MFMA32;
//           VMCNT(8) retires B-kh1(t) -- issued a FULL TILE ago -> no stall.
//   kh1(t): no staging; reads kh1 (landed per above); MFMA32;
//           VMCNT(2) retires A(t+1)x4+B-kh0(t+1)x2 -- issued a full
//           phase+MFMA-cluster ago (~1500cyc) -> no stall.
// Counted vmcnt, never 0 in loop; max 10 in flight. Buffer safety: GLDS into
// buf bn issues only after the barrier that ends tile t-1's reads of bn.
// Accumulation order per acc element unchanged (kh0 then kh1) -> numerics
// bit-identical to R4/R5. XOR swizzle + XCD map unchanged.
// ---------------------------------------------------------------------------

#define GLDS(srcp, dstp) \
    __builtin_amdgcn_global_load_lds( \
        (const __attribute__((address_space(1))) unsigned int*)(srcp), \
        (__attribute__((address_space(3))) unsigned int*)(dstp), 16, 0, 0)

#define BAR() do { asm volatile("" ::: "memory"); \
                   __builtin_amdgcn_s_barrier(); \
                   asm volatile("" ::: "memory"); } while (0)

#define VMCNT(n) asm volatile("s_waitcnt vmcnt(" #n ")" ::: "memory")

#define PH_READ_A(kh) do { \
    const ushort_t* At = As + ((b * 2 + (kh)) << 13); \
    _Pragma("unroll") \
    for (int i = 0; i < 8; i++) af[i] = *(const short8*)(At + rdA0 + (i << 9)); \
} while (0)

#define PH_READ_B4(kh) do { \
    const ushort_t* Bt = Bs + ((b * 2 + (kh)) << 13); \
    bfr[0] = *(const short8*)(Bt + rdB0); \
    bfr[1] = *(const short8*)(Bt + rdB0 + 512); \
    bfr[2] = *(const short8*)(Bt + rdB0 + 1024); \
    bfr[3] = *(const short8*)(Bt + rdB0 + 1536); \
} while (0)

#define PH_MFMA32() do { \
    __builtin_amdgcn_s_setprio(1); \
    _Pragma("unroll") \
    for (int i = 0; i < 8; i++) { \
        _Pragma("unroll") \
        for (int j = 0; j < 4; j++) \
            acc[i][j] = __builtin_amdgcn_mfma_f32_16x16x32_bf16(af[i], bfr[j], acc[i][j], 0, 0, 0); \
    } \
    __builtin_amdgcn_s_setprio(0); \
} while (0)

__global__ __launch_bounds__(512, 2)
void gemm8_kernel(const ushort_t* __restrict__ A, const ushort_t* __restrict__ B,
                  const float* __restrict__ bias, const float* __restrict__ expect,
                  float* __restrict__ C, int M, int N, int K) {
    __shared__ ushort_t As[2 * 2 * 256 * 32];   // 64 KB: [buf][kh][row 256][k 32]
    __shared__ ushort_t Bs[2 * 2 * 256 * 32];   // 64 KB

    const int pid = blockIdx.x;
    const int xcd = pid & 7;
    const int p   = pid >> 3;              // 0..63
    const int pid_n = xcd * 2 + (p & 1);   // 0..15
    const int pid_m = p >> 1;              // 0..31

    const int tid  = threadIdx.x;
    const int lane = tid & 63;
    const int wave = tid >> 6;             // 0..7
    const int wr = wave >> 2;              // 0..1  (M half)
    const int wc = wave & 3;               // 0..3  (N quarter)
    const int quad = lane >> 4;
    const int l15  = lane & 15;

    const int rslot = (quad ^ ((l15 >> 1) & 3)) * 8;              // elements
    const int rdA0 = (wr * 128 + l15) * 32 + rslot;               // + i*512
    const int rdB0 = (wc * 64 + l15) * 32 + rslot;                // + j*512

    const int srow0 = tid >> 2;                                   // 0..127
    const int ssl   = tid & 3;
    const int sc    = ssl ^ ((srow0 >> 1) & 3);

    const ushort_t* aS0 = A + ((long long)pid_m * 256 + srow0) * K + sc * 8;
    const ushort_t* aS1 = aS0 + 128LL * K;
    const ushort_t* bS0 = B + ((long long)pid_n * 256 + srow0) * K + sc * 8;
    const ushort_t* bS1 = bS0 + 128LL * K;

    f32x4 acc[8][4];
    #pragma unroll
    for (int i = 0; i < 8; i++)
        #pragma unroll
        for (int j = 0; j < 4; j++)
            acc[i][j] = (f32x4)(0.0f);

    const int NT = K / 64;                 // 64 K-tiles

    // ---- prologue: stage tile 0 into buf 0. Issue order MUST match the
    //      in-loop order (A-kh0 x2, A-kh1 x2, B-kh0 x2, B-kh1 x2) so the
    //      steady-state vmcnt counting holds on loop entry. ----
    GLDS(aS0,      As + tid * 8);
    GLDS(aS1,      As + tid * 8 + 4096);
    GLDS(aS0 + 32, As + (1 << 13) + tid * 8);
    GLDS(aS1 + 32, As + (1 << 13) + tid * 8 + 4096);
    GLDS(bS0,      Bs + tid * 8);
    GLDS(bS1,      Bs + tid * 8 + 4096);
    GLDS(bS0 + 32, Bs + (1 << 13) + tid * 8);
    GLDS(bS1 + 32, Bs + (1 << 13) + tid * 8 + 4096);
    VMCNT(2);                              // first 6 landed; B-kh1(0) in flight
    BAR();

    short8 af[8], bfr[4];

    // ---- main loop: 2 phases/tile, 1 barrier/phase, slack-correct vmcnt ----
    for (int t = 0; t < NT - 1; ++t) {
        const int b  = t & 1;
        const int bn = b ^ 1;
        const long long k1 = (long long)(t + 1) * 64;
        ushort_t* An0 = As + ((bn * 2 + 0) << 13) + tid * 8;
        ushort_t* An1 = As + ((bn * 2 + 1) << 13) + tid * 8;
        ushort_t* Bn0 = Bs + ((bn * 2 + 0) << 13) + tid * 8;
        ushort_t* Bn1 = Bs + ((bn * 2 + 1) << 13) + tid * 8;

        // phase kh0: stage ALL of tile t+1, read kh0, 32 MFMA
        GLDS(aS0 + k1,      An0);
        GLDS(aS1 + k1,      An0 + 4096);
        GLDS(aS0 + k1 + 32, An1);
        GLDS(aS1 + k1 + 32, An1 + 4096);
        GLDS(bS0 + k1,      Bn0);
        GLDS(bS1 + k1,      Bn0 + 4096);
        GLDS(bS0 + k1 + 32, Bn1);
        GLDS(bS1 + k1 + 32, Bn1 + 4096);
        PH_READ_A(0);
        PH_READ_B4(0);
        PH_MFMA32();
        VMCNT(8);          // retire B-kh1(t): issued one full TILE ago
        BAR();

        // phase kh1: no staging; read kh1, 32 MFMA
        PH_READ_A(1);
        PH_READ_B4(1);
        PH_MFMA32();
        VMCNT(2);          // retire A(t+1)+B-kh0(t+1): issued a full phase ago
        BAR();
    }

    // ---- epilogue tile NT-1 (no staging) ----
    {
        const int b = (NT - 1) & 1;
        PH_READ_A(0);
        PH_READ_B4(0);
        PH_MFMA32();
        VMCNT(0);          // drain B-kh1(NT-1)
        BAR();
        PH_READ_A(1);
        PH_READ_B4(1);
        PH_MFMA32();
    }

    // ---- C write: col = l15, row = quad*4 + reg [m89-verified] ----
    long long row0 = (long long)pid_m * 256 + wr * 128;
    int col0 = pid_n * 256 + wc * 64;
    float bj[4];
    #pragma unroll
    for (int j = 0; j < 4; j++) bj[j] = bias[col0 + j * 16 + l15];
    #pragma unroll
    for (int i = 0; i < 8; i++) {
        #pragma unroll
        for (int rr = 0; rr < 4; rr++) {
            long long row = row0 + i * 16 + quad * 4 + rr;
            float er = expect[row];
            float* Crow = C + row * (long long)N;
            #pragma unroll
            for (int j = 0; j < 4; j++)
                Crow[col0 + j * 16 + l15] = acc[i][j][rr] + bj[j] + er;
        }
    }
}

// ---------------------------------------------------------------------------
// Fallback (small ws): proven 128^2 f32-staging GEMM (R1).
// ---------------------------------------------------------------------------
#define BM 128
#define BN 128
#define BK 64

__global__ __launch_bounds__(256, 2)
void gemm_f32stage_kernel(const float* __restrict__ A, const float* __restrict__ B,
                          const float* __restrict__ bias, const float* __restrict__ expect,
                          float* __restrict__ C, int M, int N, int K) {
    __shared__ ushort_t As[BM * BK];
    __shared__ ushort_t Bs[BN * BK];

    int pid = blockIdx.x;
    const int xcd = pid & 7;
    const int p   = pid >> 3;
    int pid_n = xcd * 4 + (p & 3);
    int pid_m = p >> 2;

    const int tid  = threadIdx.x;
    const int lane = tid & 63;
    const int wave = tid >> 6;
    const int wm = (wave >> 1) * 64;
    const int wn = (wave & 1) * 64;

    const int srow = tid >> 1;
    const int chalf = (tid & 1) * 4;

    const float* a_base = A + ((long long)pid_m * BM + srow) * K + chalf * 8;
    const float* b_base = B + ((long long)pid_n * BN + srow) * K + chalf * 8;

    f32x4 acc[4][4];
    #pragma unroll
    for (int i = 0; i < 4; i++)
        #pragma unroll
        for (int j = 0; j < 4; j++)
            acc[i][j] = (f32x4)(0.0f);

    const int quad = lane >> 4;
    const int l15  = lane & 15;
    const int rlow = l15 & 7;

    for (int k0 = 0; k0 < K; k0 += BK) {
        {
            const float4* ap = (const float4*)(a_base + k0);
            const float4* bp = (const float4*)(b_base + k0);
            float4 fa[8], fb[8];
            #pragma unroll
            for (int c = 0; c < 8; c++) { fa[c] = ap[c]; fb[c] = bp[c]; }
            #pragma unroll
            for (int c = 0; c < 4; c++) {
                int sl = ((chalf + c) ^ (srow & 7)) * 8;
                *(short8*)(As + srow * BK + sl) = pack8(fa[2*c], fa[2*c+1]);
                *(short8*)(Bs + srow * BK + sl) = pack8(fb[2*c], fb[2*c+1]);
            }
        }
        __syncthreads();

        #pragma unroll
        for (int ks = 0; ks < 2; ks++) {
            int q = ks * 4 + quad;
            int sw = (q ^ rlow) * 8;
            short8 af[4], bf[4];
            #pragma unroll
            for (int i = 0; i < 4; i++) {
                af[i] = *(const short8*)(As + (wm + i * 16 + l15) * BK + sw);
                bf[i] = *(const short8*)(Bs + (wn + i * 16 + l15) * BK + sw);
            }
            #pragma unroll
            for (int i = 0; i < 4; i++)
                #pragma unroll
                for (int j = 0; j < 4; j++)
                    acc[i][j] = __builtin_amdgcn_mfma_f32_16x16x32_bf16(
                        af[i], bf[j], acc[i][j], 0, 0, 0);
        }
        __syncthreads();
    }

    long long row0 = (long long)pid_m * BM + wm;
    int col0 = pid_n * BN + wn;
    #pragma unroll
    for (int j = 0; j < 4; j++) {
        int col = col0 + j * 16 + l15;
        float bjv = bias[col];
        #pragma unroll
        for (int i = 0; i < 4; i++) {
            #pragma unroll
            for (int r = 0; r < 4; r++) {
                long long row = row0 + i * 16 + quad * 4 + r;
                C[row * N + col] = acc[i][j][r] + bjv + expect[row];
            }
        }
    }
}

extern "C" void kernel_launch(void* const* d_in, const int* in_sizes, int n_in,
                              void* d_out, int out_size, void* d_ws, size_t ws_size,
                              hipStream_t stream) {
    const float* x = (const float*)d_in[0];   // [8192, 4096] fp32
    const float* W = (const float*)d_in[1];   // [4096, 4096] fp32
    const float* b = (const float*)d_in[2];   // [4096] fp32
    const int*   q = (const int*)d_in[3];     // [8192, 1000] int32
    float* out = (float*)d_out;               // [8192, 4096] fp32

    const int M = 8192, N = 4096, K = 4096, SHOTS = 1000;

    float* expect = (float*)d_ws;             // 32 KB
    size_t need = 32768 + (size_t)M * K * 2 + (size_t)N * K * 2;  // ~96 MB

    if (ws_size >= need) {
        ushort_t* xb = (ushort_t*)((char*)d_ws + 32768);
        ushort_t* wb = xb + (size_t)M * K;
        conv_kernel<<<8192, 256, 0, stream>>>(x, xb);             // 8192*4096 f32
        conv_kernel<<<4096, 256, 0, stream>>>(W, wb);             // 4096*4096 f32
        expect_kernel<<<M / 4, 256, 0, stream>>>(q, expect, M, SHOTS);
        gemm8_kernel<<<(M / 256) * (N / 256), 512, 0, stream>>>(xb, wb, b, expect, out, M, N, K);
    } else {
        expect_kernel<<<M / 4, 256, 0, stream>>>(q, expect, M, SHOTS);
        gemm_f32stage_kernel<<<(M / BM) * (N / BN), 256, 0, stream>>>(x, W, b, expect, out, M, N, K);
    }
}

// Round 7
// 516.160 us; speedup vs baseline: 1.1270x; 1.1270x over previous
//
#include <hip/hip_runtime.h>
#include <hip/hip_bf16.h>

typedef __attribute__((ext_vector_type(8))) short short8;
typedef __attribute__((ext_vector_type(4))) float f32x4;
typedef unsigned short ushort_t;

// ---------------- prep: ONE dispatch (conv x, conv W, expect) -------------
// conv: v_cvt_pk_bf16_f32 (R6-proven, bit-identical RNE), 32 floats/thread,
// 8x float4 load -> 4x uint4 (16B) store. expect: int4 row sums.

__device__ __forceinline__ ushort_t f2bf_rne(float f) {
    unsigned u = __float_as_uint(f);
    u += 0x7FFF + ((u >> 16) & 1);   // round-to-nearest-even
    return (ushort_t)(u >> 16);
}

__device__ __forceinline__ short8 pack8(float4 a, float4 b) {
    short8 r;
    r[0] = (short)f2bf_rne(a.x); r[1] = (short)f2bf_rne(a.y);
    r[2] = (short)f2bf_rne(a.z); r[3] = (short)f2bf_rne(a.w);
    r[4] = (short)f2bf_rne(b.x); r[5] = (short)f2bf_rne(b.y);
    r[6] = (short)f2bf_rne(b.z); r[7] = (short)f2bf_rne(b.w);
    return r;
}

__device__ __forceinline__ unsigned cvt2(float lo, float hi) {
    __hip_bfloat162 p = __float22bfloat162_rn(make_float2(lo, hi));
    return *reinterpret_cast<unsigned*>(&p);   // lo in low 16 bits
}

__global__ void prep_kernel(const float* __restrict__ x, ushort_t* __restrict__ xb,
                            const float* __restrict__ w, ushort_t* __restrict__ wb,
                            const int* __restrict__ q, float* __restrict__ e,
                            int blocks_x, int blocks_w, int shots) {
    int bid = blockIdx.x;
    if (bid < blocks_x + blocks_w) {
        const float* src; ushort_t* dst; long long base;
        if (bid < blocks_x) { src = x; dst = xb; base = (long long)bid * 1024; }
        else { src = w; dst = wb; base = (long long)(bid - blocks_x) * 1024; }
        const float4* s4 = (const float4*)src;
        uint4* d4 = (uint4*)dst;
        #pragma unroll
        for (int c = 0; c < 4; c++) {
            long long u = base + c * 256 + threadIdx.x;   // 8-float unit
            float4 a  = s4[2 * u];
            float4 b2 = s4[2 * u + 1];
            uint4 r;
            r.x = cvt2(a.x,  a.y);
            r.y = cvt2(a.z,  a.w);
            r.z = cvt2(b2.x, b2.y);
            r.w = cvt2(b2.z, b2.w);
            d4[u] = r;                                    // 16B store
        }
    } else {
        int eb = bid - (blocks_x + blocks_w);
        int row = eb * 4 + (threadIdx.x >> 6);
        int lane = threadIdx.x & 63;
        const int4* rp4 = (const int4*)(q + (long long)row * shots);
        int nvec = shots >> 2;                 // 250
        int s = 0;
        for (int j = lane; j < nvec; j += 64) {
            int4 v = rp4[j];
            s += v.x + v.y + v.z + v.w;
        }
        #pragma unroll
        for (int off = 32; off; off >>= 1) s += __shfl_down(s, off, 64);
        if (lane == 0) e[row] = (float)s * (1.0f / (1000.0f * 15.0f));
    }
}

// ---------------------------------------------------------------------------
// ROUND-11 GEMM: byte-exact revert to the R4 schedule (measured 246us,
// MfmaUtil 50%, 0 bank conflicts). R5/R6 de-lockstep variants both regressed
// (308/333us) -- m196's lesson confirmed on this kernel: the 4-phase barrier
// rhythm with per-phase {ds_read, 2xGLDS, BAR, 16 MFMA, BAR} IS the fast
// structure at this tile shape; do not coarsen it.
// 256x256 tile, BK=64, 8 waves (2Mx4N), LDS [2buf][2kh][256][32] = 128KB.
// Counted vmcnt(4) at P1/P3 end only (never 0 in loop). XOR-swizzled slots
// (0 conflicts measured). XCD-aware block map.
// ---------------------------------------------------------------------------

#define GLDS(srcp, dstp) \
    __builtin_amdgcn_global_load_lds( \
        (const __attribute__((address_space(1))) unsigned int*)(srcp), \
        (__attribute__((address_space(3))) unsigned int*)(dstp), 16, 0, 0)

#define BAR() do { asm volatile("" ::: "memory"); \
                   __builtin_amdgcn_s_barrier(); \
                   asm volatile("" ::: "memory"); } while (0)

#define VMCNT(n) asm volatile("s_waitcnt vmcnt(" #n ")" ::: "memory")

#define PH_READ_A(kh) do { \
    const ushort_t* At = As + ((b * 2 + (kh)) << 13); \
    _Pragma("unroll") \
    for (int i = 0; i < 8; i++) af[i] = *(const short8*)(At + rdA0 + (i << 9)); \
} while (0)

#define PH_READ_B(kh, nh) do { \
    const ushort_t* Bt = Bs + ((b * 2 + (kh)) << 13); \
    bfr[0] = *(const short8*)(Bt + rdB0 + ((nh) << 10)); \
    bfr[1] = *(const short8*)(Bt + rdB0 + ((nh) << 10) + 512); \
} while (0)

#define PH_MFMA(nh) do { \
    __builtin_amdgcn_s_setprio(1); \
    _Pragma("unroll") \
    for (int i = 0; i < 8; i++) { \
        acc[i][(nh) * 2]     = __builtin_amdgcn_mfma_f32_16x16x32_bf16(af[i], bfr[0], acc[i][(nh) * 2], 0, 0, 0); \
        acc[i][(nh) * 2 + 1] = __builtin_amdgcn_mfma_f32_16x16x32_bf16(af[i], bfr[1], acc[i][(nh) * 2 + 1], 0, 0, 0); \
    } \
    __builtin_amdgcn_s_setprio(0); \
} while (0)

__global__ __launch_bounds__(512, 2)
void gemm8_kernel(const ushort_t* __restrict__ A, const ushort_t* __restrict__ B,
                  const float* __restrict__ bias, const float* __restrict__ expect,
                  float* __restrict__ C, int M, int N, int K) {
    __shared__ ushort_t As[2 * 2 * 256 * 32];   // 64 KB: [buf][kh][row 256][k 32]
    __shared__ ushort_t Bs[2 * 2 * 256 * 32];   // 64 KB

    const int pid = blockIdx.x;
    const int xcd = pid & 7;
    const int p   = pid >> 3;              // 0..63
    const int pid_n = xcd * 2 + (p & 1);   // 0..15
    const int pid_m = p >> 1;              // 0..31

    const int tid  = threadIdx.x;
    const int lane = tid & 63;
    const int wave = tid >> 6;             // 0..7
    const int wr = wave >> 2;              // 0..1  (M half)
    const int wc = wave & 3;               // 0..3  (N quarter)
    const int quad = lane >> 4;
    const int l15  = lane & 15;

    const int rslot = (quad ^ ((l15 >> 1) & 3)) * 8;              // elements
    const int rdA0 = (wr * 128 + l15) * 32 + rslot;               // + i*512
    const int rdB0 = (wc * 64 + l15) * 32 + rslot;                // + nh*1024 + j*512

    const int srow0 = tid >> 2;                                   // 0..127
    const int ssl   = tid & 3;
    const int sc    = ssl ^ ((srow0 >> 1) & 3);

    const ushort_t* aS0 = A + ((long long)pid_m * 256 + srow0) * K + sc * 8;
    const ushort_t* aS1 = aS0 + 128LL * K;
    const ushort_t* bS0 = B + ((long long)pid_n * 256 + srow0) * K + sc * 8;
    const ushort_t* bS1 = bS0 + 128LL * K;

    f32x4 acc[8][4];
    #pragma unroll
    for (int i = 0; i < 8; i++)
        #pragma unroll
        for (int j = 0; j < 4; j++)
            acc[i][j] = (f32x4)(0.0f);

    const int NT = K / 64;                 // 64 K-tiles

    // ---- prologue: stage tile 0 into buf 0 (order A0,B0,A1,B1), drain ----
    GLDS(aS0,      As + tid * 8);
    GLDS(aS1,      As + tid * 8 + 4096);
    GLDS(bS0,      Bs + tid * 8);
    GLDS(bS1,      Bs + tid * 8 + 4096);
    GLDS(aS0 + 32, As + (1 << 13) + tid * 8);
    GLDS(aS1 + 32, As + (1 << 13) + tid * 8 + 4096);
    GLDS(bS0 + 32, Bs + (1 << 13) + tid * 8);
    GLDS(bS1 + 32, Bs + (1 << 13) + tid * 8 + 4096);
    VMCNT(0);
    BAR();

    short8 af[8], bfr[2];

    // ---- main loop: 4 phases/tile, vmcnt(4) at P1/P3 end ----
    for (int t = 0; t < NT - 1; ++t) {
        const int b  = t & 1;
        const int bn = b ^ 1;
        const long long k1 = (long long)(t + 1) * 64;
        ushort_t* An0 = As + ((bn * 2 + 0) << 13) + tid * 8;
        ushort_t* An1 = As + ((bn * 2 + 1) << 13) + tid * 8;
        ushort_t* Bn0 = Bs + ((bn * 2 + 0) << 13) + tid * 8;
        ushort_t* Bn1 = Bs + ((bn * 2 + 1) << 13) + tid * 8;

        // P0: kh0, nh0 + stage A-kh0(t+1)
        PH_READ_A(0);
        PH_READ_B(0, 0);
        GLDS(aS0 + k1, An0);
        GLDS(aS1 + k1, An0 + 4096);
        BAR();
        PH_MFMA(0);
        BAR();

        // P1: kh0, nh1 (af reused) + stage B-kh0(t+1)
        PH_READ_B(0, 1);
        GLDS(bS0 + k1, Bn0);
        GLDS(bS1 + k1, Bn0 + 4096);
        BAR();
        PH_MFMA(1);
        VMCNT(4);
        BAR();

        // P2: kh1, nh0 + stage A-kh1(t+1)
        PH_READ_A(1);
        PH_READ_B(1, 0);
        GLDS(aS0 + k1 + 32, An1);
        GLDS(aS1 + k1 + 32, An1 + 4096);
        BAR();
        PH_MFMA(0);
        BAR();

        // P3: kh1, nh1 + stage B-kh1(t+1)
        PH_READ_B(1, 1);
        GLDS(bS0 + k1 + 32, Bn1);
        GLDS(bS1 + k1 + 32, Bn1 + 4096);
        BAR();
        PH_MFMA(1);
        VMCNT(4);
        BAR();
    }

    // ---- epilogue tile NT-1 (no staging; drain remaining 4 before kh1) ----
    {
        const int b = (NT - 1) & 1;
        PH_READ_A(0);
        PH_READ_B(0, 0);
        BAR();
        PH_MFMA(0);
        BAR();
        PH_READ_B(0, 1);
        BAR();
        PH_MFMA(1);
        VMCNT(0);
        BAR();
        PH_READ_A(1);
        PH_READ_B(1, 0);
        BAR();
        PH_MFMA(0);
        BAR();
        PH_READ_B(1, 1);
        BAR();
        PH_MFMA(1);
    }

    // ---- C write: col = l15, row = quad*4 + reg [m89-verified] ----
    long long row0 = (long long)pid_m * 256 + wr * 128;
    int col0 = pid_n * 256 + wc * 64;
    float bj[4];
    #pragma unroll
    for (int j = 0; j < 4; j++) bj[j] = bias[col0 + j * 16 + l15];
    #pragma unroll
    for (int i = 0; i < 8; i++) {
        #pragma unroll
        for (int rr = 0; rr < 4; rr++) {
            long long row = row0 + i * 16 + quad * 4 + rr;
            float er = expect[row];
            float* Crow = C + row * (long long)N;
            #pragma unroll
            for (int j = 0; j < 4; j++)
                Crow[col0 + j * 16 + l15] = acc[i][j][rr] + bj[j] + er;
        }
    }
}

// ---------------------------------------------------------------------------
// Fallback (small ws): proven 128^2 f32-staging GEMM (R1).
// ---------------------------------------------------------------------------
#define BM 128
#define BN 128
#define BK 64

__global__ void expect_kernel(const int* __restrict__ q, float* __restrict__ e,
                              int rows, int shots) {
    int row = blockIdx.x * (blockDim.x >> 6) + (threadIdx.x >> 6);
    int lane = threadIdx.x & 63;
    if (row >= rows) return;
    const int* rp = q + (long long)row * shots;
    int s = 0;
    for (int j = lane; j < shots; j += 64) s += rp[j];
    #pragma unroll
    for (int off = 32; off; off >>= 1) s += __shfl_down(s, off, 64);
    if (lane == 0) e[row] = (float)s * (1.0f / (1000.0f * 15.0f));
}

__global__ __launch_bounds__(256, 2)
void gemm_f32stage_kernel(const float* __restrict__ A, const float* __restrict__ B,
                          const float* __restrict__ bias, const float* __restrict__ expect,
                          float* __restrict__ C, int M, int N, int K) {
    __shared__ ushort_t As[BM * BK];
    __shared__ ushort_t Bs[BN * BK];

    int pid = blockIdx.x;
    const int xcd = pid & 7;
    const int p   = pid >> 3;
    int pid_n = xcd * 4 + (p & 3);
    int pid_m = p >> 2;

    const int tid  = threadIdx.x;
    const int lane = tid & 63;
    const int wave = tid >> 6;
    const int wm = (wave >> 1) * 64;
    const int wn = (wave & 1) * 64;

    const int srow = tid >> 1;
    const int chalf = (tid & 1) * 4;

    const float* a_base = A + ((long long)pid_m * BM + srow) * K + chalf * 8;
    const float* b_base = B + ((long long)pid_n * BN + srow) * K + chalf * 8;

    f32x4 acc[4][4];
    #pragma unroll
    for (int i = 0; i < 4; i++)
        #pragma unroll
        for (int j = 0; j < 4; j++)
            acc[i][j] = (f32x4)(0.0f);

    const int quad = lane >> 4;
    const int l15  = lane & 15;
    const int rlow = l15 & 7;

    for (int k0 = 0; k0 < K; k0 += BK) {
        {
            const float4* ap = (const float4*)(a_base + k0);
            const float4* bp = (const float4*)(b_base + k0);
            float4 fa[8], fb[8];
            #pragma unroll
            for (int c = 0; c < 8; c++) { fa[c] = ap[c]; fb[c] = bp[c]; }
            #pragma unroll
            for (int c = 0; c < 4; c++) {
                int sl = ((chalf + c) ^ (srow & 7)) * 8;
                *(short8*)(As + srow * BK + sl) = pack8(fa[2*c], fa[2*c+1]);
                *(short8*)(Bs + srow * BK + sl) = pack8(fb[2*c], fb[2*c+1]);
            }
        }
        __syncthreads();

        #pragma unroll
        for (int ks = 0; ks < 2; ks++) {
            int q = ks * 4 + quad;
            int sw = (q ^ rlow) * 8;
            short8 af[4], bf[4];
            #pragma unroll
            for (int i = 0; i < 4; i++) {
                af[i] = *(const short8*)(As + (wm + i * 16 + l15) * BK + sw);
                bf[i] = *(const short8*)(Bs + (wn + i * 16 + l15) * BK + sw);
            }
            #pragma unroll
            for (int i = 0; i < 4; i++)
                #pragma unroll
                for (int j = 0; j < 4; j++)
                    acc[i][j] = __builtin_amdgcn_mfma_f32_16x16x32_bf16(
                        af[i], bf[j], acc[i][j], 0, 0, 0);
        }
        __syncthreads();
    }

    long long row0 = (long long)pid_m * BM + wm;
    int col0 = pid_n * BN + wn;
    #pragma unroll
    for (int j = 0; j < 4; j++) {
        int col = col0 + j * 16 + l15;
        float bjv = bias[col];
        #pragma unroll
        for (int i = 0; i < 4; i++) {
            #pragma unroll
            for (int r = 0; r < 4; r++) {
                long long row = row0 + i * 16 + quad * 4 + r;
                C[row * N + col] = acc[i][j][r] + bjv + expect[row];
            }
        }
    }
}

extern "C" void kernel_launch(void* const* d_in, const int* in_sizes, int n_in,
                              void* d_out, int out_size, void* d_ws, size_t ws_size,
                              hipStream_t stream) {
    const float* x = (const float*)d_in[0];   // [8192, 4096] fp32
    const float* W = (const float*)d_in[1];   // [4096, 4096] fp32
    const float* b = (const float*)d_in[2];   // [4096] fp32
    const int*   q = (const int*)d_in[3];     // [8192, 1000] int32
    float* out = (float*)d_out;               // [8192, 4096] fp32

    const int M = 8192, N = 4096, K = 4096, SHOTS = 1000;

    float* expect = (float*)d_ws;             // 32 KB
    size_t need = 32768 + (size_t)M * K * 2 + (size_t)N * K * 2;  // ~96 MB

    if (ws_size >= need) {
        ushort_t* xb = (ushort_t*)((char*)d_ws + 32768);
        ushort_t* wb = xb + (size_t)M * K;
        int blocks_x = (int)((long long)M * K / 32 / 256);   // 4096 (32 floats/thr)
        int blocks_w = (int)((long long)N * K / 32 / 256);   // 2048
        int blocks_e = M / 4;                                // 2048
        prep_kernel<<<blocks_x + blocks_w + blocks_e, 256, 0, stream>>>(
            x, xb, W, wb, q, expect, blocks_x, blocks_w, SHOTS);
        gemm8_kernel<<<(M / 256) * (N / 256), 512, 0, stream>>>(xb, wb, b, expect, out, M, N, K);
    } else {
        expect_kernel<<<M / 4, 256, 0, stream>>>(q, expect, M, SHOTS);
        gemm_f32stage_kernel<<<(M / BM) * (N / BN), 256, 0, stream>>>(x, W, b, expect, out, M, N, K);
    }
}